// Round 1
// baseline (359.380 us; speedup 1.0000x reference)
//
#include <hip/hip_runtime.h>
#include <math.h>

#define B_ROWS 262144
#define NCOL 99

// Block id per column: -1 = continuous (MSE) col, 0..7 = CE block index.
// Every column is one or the other (cont cols = {0,55,56,57}).
__device__ constexpr signed char BLK[99] = {
  -1,                                        // 0
  0,0,0,0,0,0,0,                             // 1-7
  1,1,1,1,1,1,1,1,1,1,1,1,1,1,1,1,           // 8-23
  2,2,2,2,2,2,2,                             // 24-30
  3,3,3,3,3,3,3,3,3,3,3,3,3,3,               // 31-44
  4,4,4,4,4,4,                               // 45-50
  5,5,                                       // 51-52
  6,6,                                       // 53-54
  -1,-1,-1,                                  // 55-57
  7,7,7,7,7,7,7,7,7,7,7,7,7,7,7,7,7,7,7,7,7, // 58-78
  7,7,7,7,7,7,7,7,7,7,7,7,7,7,7,7,7,7,7,7    // 79-98
};

// ws layout (uint32 cells):
// [0..9]   column min (monotone-mapped uint)
// [10..19] column max (monotone-mapped uint)
// [20] mse_sum (f32)  [21] dot_sum (f32)  [22] lse_sum (f32)
// [23] m_count (u32)  [24] f_count (u32)
// [32..131] m_hist[100] (u32)   [132..231] f_hist[100] (u32)

__global__ void k_init(unsigned int* ws) {
  for (int i = threadIdx.x; i < 232; i += 256)
    ws[i] = (i < 10) ? 0xFFFFFFFFu : 0u;
}

__device__ __forceinline__ unsigned int map_f(float x) {
  unsigned int b = __float_as_uint(x);
  return (b & 0x80000000u) ? ~b : (b | 0x80000000u);
}
__device__ __forceinline__ float unmap_f(unsigned int u) {
  unsigned int b = (u & 0x80000000u) ? (u ^ 0x80000000u) : ~u;
  return __uint_as_float(b);
}

// Pass over data_encoded: per-column min/max (cols 0..9) + sex counts (col 11).
// blockDim=192 (multiple of both 64 and 12) so each thread's column is fixed.
__global__ __launch_bounds__(192) void k_minmax(const float* __restrict__ enc,
                                                unsigned int* ws) {
  __shared__ unsigned int smn[10], smx[10], scnt[2];
  int tid = threadIdx.x;
  if (tid < 10) { smn[tid] = 0xFFFFFFFFu; smx[tid] = 0u; }
  if (tid < 2) scnt[tid] = 0u;
  __syncthreads();

  int g = blockIdx.x * 192 + tid;
  int S = gridDim.x * 192;        // multiple of 12
  int col = g % 12;               // constant for this thread across iterations
  unsigned int mn = 0xFFFFFFFFu, mx = 0u, cm = 0, cf = 0;
  for (int e = g; e < B_ROWS * 12; e += S) {
    float x = enc[e];
    unsigned int u = map_f(x);
    if (col < 10) { mn = min(mn, u); mx = max(mx, u); }
    else if (col == 11) { cm += (x == 0.0f); cf += (x == 1.0f); }
  }
  if (col < 10) { atomicMin(&smn[col], mn); atomicMax(&smx[col], mx); }
  else if (col == 11) { atomicAdd(&scnt[0], cm); atomicAdd(&scnt[1], cf); }
  __syncthreads();
  if (tid < 10) {
    atomicMin(&ws[tid], smn[tid]);
    atomicMax(&ws[10 + tid], smx[tid]);
  }
  if (tid == 64) atomicAdd(&ws[23], scnt[0]);
  if (tid == 65) atomicAdd(&ws[24], scnt[1]);
}

// Histogram pass over data_encoded (needs min/max from ws).
__global__ __launch_bounds__(256) void k_hist(const float* __restrict__ enc,
                                              unsigned int* ws) {
  __shared__ float tile[256 * 12];
  __shared__ unsigned int h[200];
  __shared__ float mnv[10], wid[10];
  int tid = threadIdx.x;
  for (int i = tid; i < 200; i += 256) h[i] = 0u;
  if (tid < 10) {
    float mn = unmap_f(ws[tid]);
    float mx = unmap_f(ws[10 + tid]);
    mnv[tid] = mn;
    wid[tid] = fmaxf(mx - mn, 1e-12f);
  }
  size_t r0 = (size_t)blockIdx.x * 256;
  const float4* src = (const float4*)(enc + r0 * 12);  // r0*48 B: 16B aligned
  float4* dst = (float4*)tile;
  for (int i = tid; i < 768; i += 256) dst[i] = src[i];
  __syncthreads();

  float s = tile[tid * 12 + 11];
  int base = (s == 0.0f) ? 0 : ((s == 1.0f) ? 100 : -1);
  if (base >= 0) {
    #pragma unroll
    for (int c = 0; c < 10; c++) {
      float x = tile[tid * 12 + c];
      float v = (x - mnv[c]) / wid[c] * 10.0f;   // same op order as reference
      int bi = (int)floorf(v);
      bi = min(max(bi, 0), 9);
      atomicAdd(&h[base + c * 10 + bi], 1u);
    }
  }
  __syncthreads();
  for (int i = tid; i < 200; i += 256) if (h[i]) atomicAdd(&ws[32 + i], h[i]);
}

// Fused main pass: one read of decoded + true.
// Per block: 256 rows. 3 column-chunks of 33 staged in LDS (decoded only).
// MSE/dot computed at load time (flat global sums); per-row streaming
// sum-exp per CE block with state persisting across chunks.
#define W 33
__global__ __launch_bounds__(256) void k_main(const float* __restrict__ d,
                                              const float* __restrict__ t,
                                              unsigned int* ws) {
  __shared__ float tile[256 * W];
  __shared__ float red[12];
  int tid = threadIdx.x;
  size_t r0 = (size_t)blockIdx.x * 256;
  const float* dbase = d + r0 * NCOL;
  const float* tbase = t + r0 * NCOL;

  float mse = 0.f, dot = 0.f, ce = 0.f;
  float Z = 0.f;
  int cur = -1;

  #pragma unroll
  for (int ch = 0; ch < 3; ch++) {
    const int c0 = ch * W;
    // --- staging + elementwise terms ---
    for (int i = tid; i < 256 * W; i += 256) {
      int r = i / W;
      int c = i - r * W;
      int ga = r * NCOL + c0 + c;
      float xd = dbase[ga];
      float xt = tbase[ga];
      tile[i] = xd;
      int col = c0 + c;
      bool cont = (col == 0) | ((unsigned)(col - 55) <= 2u);
      float diff = xd - xt;
      if (cont) mse += diff * diff;
      else      dot += xt * xd;
    }
    __syncthreads();
    // --- per-row streaming logsumexp ---
    const float* row = &tile[tid * W];   // stride 33 ≡ 1 mod 32: conflict-free
    #pragma unroll
    for (int c = 0; c < W; c++) {
      int col = c0 + c;
      int b = BLK[col];
      if (b != cur) {
        if (cur >= 0) ce += __logf(Z);
        Z = 0.f;
        cur = b;
      }
      if (b >= 0) Z += __expf(row[c]);
    }
    __syncthreads();
  }
  if (cur >= 0) ce += __logf(Z);

  // block reduction of the three partial sums
  #pragma unroll
  for (int off = 32; off; off >>= 1) {
    mse += __shfl_down(mse, off);
    dot += __shfl_down(dot, off);
    ce  += __shfl_down(ce,  off);
  }
  int wave = tid >> 6, lane = tid & 63;
  if (lane == 0) { red[wave] = mse; red[4 + wave] = dot; red[8 + wave] = ce; }
  __syncthreads();
  if (tid == 0) {
    float m  = red[0] + red[1] + red[2]  + red[3];
    float dd = red[4] + red[5] + red[6]  + red[7];
    float cc = red[8] + red[9] + red[10] + red[11];
    atomicAdd((float*)&ws[20], m);
    atomicAdd((float*)&ws[21], dd);
    atomicAdd((float*)&ws[22], cc);
  }
}

__global__ void k_final(const unsigned int* __restrict__ ws, float* out) {
  __shared__ float part[256];
  int tid = threadIdx.x;
  float mcnt = fmaxf((float)ws[23], 1.0f);
  float fcnt = fmaxf((float)ws[24], 1.0f);
  float term = 0.f;
  if (tid < 100) {
    unsigned int mc = ws[32 + tid], fc = ws[132 + tid];
    if (mc > 0 && fc > 0) {
      float p = (float)mc / mcnt;
      float q = (float)fc / fcnt;
      term = p * logf(p / q);
    }
  }
  part[tid] = term;
  __syncthreads();
  for (int s = 128; s; s >>= 1) {
    if (tid < s) part[tid] += part[tid + s];
    __syncthreads();
  }
  if (tid == 0) {
    float kld = part[0];
    const float invB = 1.0f / (float)B_ROWS;
    float mse = __uint_as_float(ws[20]) * invB;
    float ce  = (__uint_as_float(ws[22]) - __uint_as_float(ws[21])) * invB;
    float akld = 0.5f * kld;
    out[0] = 0.5f * (mse + ce) + akld;
    out[1] = mse;
    out[2] = ce;
    out[3] = akld;
  }
}

extern "C" void kernel_launch(void* const* d_in, const int* in_sizes, int n_in,
                              void* d_out, int out_size, void* d_ws, size_t ws_size,
                              hipStream_t stream) {
  const float* enc = (const float*)d_in[0];   // data_encoded (B,12)
  const float* dec = (const float*)d_in[1];   // data_decoded (B,99)
  const float* tru = (const float*)d_in[2];   // data_true    (B,99)
  // d_in[3] = label_true (unused), d_in[4] = batch_size (fixed 262144)
  unsigned int* ws = (unsigned int*)d_ws;
  float* out = (float*)d_out;

  hipLaunchKernelGGL(k_init,   dim3(1),    dim3(256), 0, stream, ws);
  hipLaunchKernelGGL(k_minmax, dim3(1024), dim3(192), 0, stream, enc, ws);
  hipLaunchKernelGGL(k_hist,   dim3(1024), dim3(256), 0, stream, enc, ws);
  hipLaunchKernelGGL(k_main,   dim3(1024), dim3(256), 0, stream, dec, tru, ws);
  hipLaunchKernelGGL(k_final,  dim3(1),    dim3(256), 0, stream, ws, out);
}

// Round 2
// 274.737 us; speedup vs baseline: 1.3081x; 1.3081x over previous
//
#include <hip/hip_runtime.h>
#include <math.h>

#define B_ROWS 262144

// ws layout (4-byte cells):
//  A: minmax partials: 128 blocks x 22 cells (mapped-uint min[10], max[10], cm, cf)
//  B: hist partials:   128 blocks x 200 u32   at offset 2816
//  C: main partials:   3 x 1024 f32           at offset 28416
#define WS_A 0
#define WS_B 2816
#define WS_C 28416

__device__ __forceinline__ unsigned int map_f(float x) {
  unsigned int b = __float_as_uint(x);
  return (b & 0x80000000u) ? ~b : (b | 0x80000000u);
}
__device__ __forceinline__ float unmap_f(unsigned int u) {
  unsigned int b = (u & 0x80000000u) ? (u ^ 0x80000000u) : ~u;
  return __uint_as_float(b);
}

// ---------------- pass 1 over data_encoded: per-column min/max + sex counts ----
// 128 blocks x 256 threads, 8 rows/thread, float4 row loads, register reduce,
// per-block partial written to private ws slots (NO contended atomics).
__global__ __launch_bounds__(256) void k_minmax(const float* __restrict__ enc,
                                                unsigned int* __restrict__ ws) {
  int tid = threadIdx.x, bid = blockIdx.x;
  const float4* e4 = (const float4*)enc;
  float mn[10], mx[10];
  #pragma unroll
  for (int j = 0; j < 10; j++) { mn[j] = 1e30f; mx[j] = -1e30f; }
  unsigned int cm = 0, cf = 0;
  #pragma unroll
  for (int i = 0; i < 8; i++) {
    size_t g = (size_t)bid * 2048 + i * 256 + tid;
    float4 a = e4[g * 3 + 0], b = e4[g * 3 + 1], c = e4[g * 3 + 2];
    float v[12] = {a.x,a.y,a.z,a.w,b.x,b.y,b.z,b.w,c.x,c.y,c.z,c.w};
    #pragma unroll
    for (int j = 0; j < 10; j++) { mn[j] = fminf(mn[j], v[j]); mx[j] = fmaxf(mx[j], v[j]); }
    cm += (v[11] == 0.0f); cf += (v[11] == 1.0f);
  }
  // 64-lane butterfly
  #pragma unroll
  for (int off = 32; off; off >>= 1) {
    #pragma unroll
    for (int j = 0; j < 10; j++) {
      mn[j] = fminf(mn[j], __shfl_xor(mn[j], off));
      mx[j] = fmaxf(mx[j], __shfl_xor(mx[j], off));
    }
    cm += __shfl_xor(cm, off); cf += __shfl_xor(cf, off);
  }
  __shared__ float smn[4][10], smx[4][10];
  __shared__ unsigned int sc[4][2];
  int wave = tid >> 6, lane = tid & 63;
  if (lane == 0) {
    #pragma unroll
    for (int j = 0; j < 10; j++) { smn[wave][j] = mn[j]; smx[wave][j] = mx[j]; }
    sc[wave][0] = cm; sc[wave][1] = cf;
  }
  __syncthreads();
  unsigned int* out = ws + WS_A + bid * 22;
  if (tid < 10) {
    float m = fminf(fminf(smn[0][tid], smn[1][tid]), fminf(smn[2][tid], smn[3][tid]));
    out[tid] = map_f(m);
  } else if (tid < 20) {
    int j = tid - 10;
    float m = fmaxf(fmaxf(smx[0][j], smx[1][j]), fmaxf(smx[2][j], smx[3][j]));
    out[tid] = map_f(m);
  } else if (tid < 22) {
    int j = tid - 20;
    out[tid] = sc[0][j] + sc[1][j] + sc[2][j] + sc[3][j];
  }
}

// ---------------- pass 2 over data_encoded: histograms ----------------
// Reduces the 128 minmax partials at block start, then LDS histogram,
// per-block partial hist written to private slots.
__global__ __launch_bounds__(256) void k_hist(const float* __restrict__ enc,
                                              unsigned int* __restrict__ ws) {
  __shared__ float mnv[10], wid[10];
  __shared__ unsigned int h[200];
  int tid = threadIdx.x, bid = blockIdx.x;
  for (int i = tid; i < 200; i += 256) h[i] = 0u;
  if (tid < 10) {
    unsigned int umn = 0xFFFFFFFFu, umx = 0u;
    #pragma unroll 4
    for (int b = 0; b < 128; b++) {
      umn = min(umn, ws[WS_A + b * 22 + tid]);
      umx = max(umx, ws[WS_A + b * 22 + 10 + tid]);
    }
    float mn = unmap_f(umn);
    mnv[tid] = mn;
    wid[tid] = fmaxf(unmap_f(umx) - mn, 1e-12f);
  }
  __syncthreads();
  const float4* e4 = (const float4*)enc;
  #pragma unroll
  for (int i = 0; i < 8; i++) {
    size_t g = (size_t)bid * 2048 + i * 256 + tid;
    float4 a = e4[g * 3 + 0], b = e4[g * 3 + 1], c = e4[g * 3 + 2];
    float v[12] = {a.x,a.y,a.z,a.w,b.x,b.y,b.z,b.w,c.x,c.y,c.z,c.w};
    int base = (v[11] == 0.0f) ? 0 : ((v[11] == 1.0f) ? 100 : -1);
    if (base >= 0) {
      #pragma unroll
      for (int cc = 0; cc < 10; cc++) {
        float t = (v[cc] - mnv[cc]) / wid[cc] * 10.0f;  // reference op order
        int bi = min(max((int)floorf(t), 0), 9);
        atomicAdd(&h[base + cc * 10 + bi], 1u);
      }
    }
  }
  __syncthreads();
  if (tid < 200) ws[WS_B + bid * 200 + tid] = h[tid];
}

// ---------------- main pass over decoded + true ----------------
// 1024 blocks x 2 tiles; tile = 128 rows x 99 cols. Flat float4 staging of
// both arrays; MSE/dot at load time; decoded -> LDS tile padded to 101
// (stride 101 => conflict-free column reads). LSE: waves 0-1 take cols 0-50,
// waves 2-3 take cols 51-98 (no CE block spans col 51). Per-block partials
// to private ws slots.
__global__ __launch_bounds__(256) void k_main(const float* __restrict__ d,
                                              const float* __restrict__ t,
                                              unsigned int* __restrict__ ws) {
  __shared__ float tile[128 * 101];
  __shared__ float red[12];
  int tid = threadIdx.x, bid = blockIdx.x;
  float mse = 0.f, dot = 0.f, ce = 0.f;

  #pragma unroll
  for (int it = 0; it < 2; it++) {
    int tileIdx = bid + it * 1024;
    const float4* d4 = (const float4*)(d + (size_t)tileIdx * 12672);
    const float4* t4 = (const float4*)(t + (size_t)tileIdx * 12672);
    // ---- staging + elementwise terms (3168 float4 per array) ----
    for (int f = tid; f < 3168; f += 256) {
      float4 xd = d4[f];
      float4 xt = t4[f];
      int e = f * 4;
      int r = e / 99;            // magic-mul, compile-time constant divisor
      int c = e - r * 99;
      float dv[4] = {xd.x, xd.y, xd.z, xd.w};
      float tv[4] = {xt.x, xt.y, xt.z, xt.w};
      #pragma unroll
      for (int k = 0; k < 4; k++) {
        int cc = c + k, rr = r;
        if (cc >= 99) { cc -= 99; rr++; }
        bool cont = (cc == 0) | ((unsigned)(cc - 55) <= 2u);
        float diff = dv[k] - tv[k];
        if (cont) mse += diff * diff;
        else      dot += tv[k] * dv[k];
        tile[rr * 101 + cc] = dv[k];
      }
    }
    __syncthreads();
    // ---- per-row streaming logsumexp (wave-uniform part split) ----
    if (tid < 128) {
      const float* row = &tile[tid * 101];
      float Z;
      Z = 0.f;
      #pragma unroll
      for (int c = 1; c < 8; c++) Z += __expf(row[c]);
      ce += __logf(Z);
      Z = 0.f;
      #pragma unroll
      for (int c = 8; c < 24; c++) Z += __expf(row[c]);
      ce += __logf(Z);
      Z = 0.f;
      #pragma unroll
      for (int c = 24; c < 31; c++) Z += __expf(row[c]);
      ce += __logf(Z);
      Z = 0.f;
      #pragma unroll
      for (int c = 31; c < 45; c++) Z += __expf(row[c]);
      ce += __logf(Z);
      Z = 0.f;
      #pragma unroll
      for (int c = 45; c < 51; c++) Z += __expf(row[c]);
      ce += __logf(Z);
    } else {
      const float* row = &tile[(tid - 128) * 101];
      float Z;
      Z = 0.f;
      #pragma unroll
      for (int c = 51; c < 53; c++) Z += __expf(row[c]);
      ce += __logf(Z);
      Z = 0.f;
      #pragma unroll
      for (int c = 53; c < 55; c++) Z += __expf(row[c]);
      ce += __logf(Z);
      Z = 0.f;
      #pragma unroll
      for (int c = 58; c < 99; c++) Z += __expf(row[c]);
      ce += __logf(Z);
    }
    __syncthreads();  // tile reused next iteration
  }

  // ---- block reduction, single non-atomic partial write ----
  #pragma unroll
  for (int off = 32; off; off >>= 1) {
    mse += __shfl_xor(mse, off);
    dot += __shfl_xor(dot, off);
    ce  += __shfl_xor(ce,  off);
  }
  int wave = tid >> 6, lane = tid & 63;
  if (lane == 0) { red[wave] = mse; red[4 + wave] = dot; red[8 + wave] = ce; }
  __syncthreads();
  if (tid == 0) {
    float* C = (float*)(ws + WS_C);
    C[bid]        = red[0] + red[1] + red[2]  + red[3];
    C[1024 + bid] = red[4] + red[5] + red[6]  + red[7];
    C[2048 + bid] = red[8] + red[9] + red[10] + red[11];
  }
}

// ---------------- finalize ----------------
__global__ __launch_bounds__(256) void k_final(const unsigned int* __restrict__ ws,
                                               float* __restrict__ out) {
  __shared__ float h[200];
  __shared__ float part[256];
  __shared__ float red3[12];
  __shared__ float cnts[2];
  int tid = threadIdx.x;
  // reduce hist partials (coalesced across t within each b)
  if (tid < 200) {
    unsigned int s = 0;
    #pragma unroll 4
    for (int b = 0; b < 128; b++) s += ws[WS_B + b * 200 + tid];
    h[tid] = (float)s;
  }
  if (tid == 200 || tid == 201) {
    unsigned int s = 0;
    #pragma unroll 4
    for (int b = 0; b < 128; b++) s += ws[WS_A + b * 22 + 20 + (tid - 200)];
    cnts[tid - 200] = fmaxf((float)s, 1.0f);
  }
  // reduce main partials
  const float* C = (const float*)(ws + WS_C);
  float msum = 0.f, dsum = 0.f, csum = 0.f;
  for (int i = tid; i < 1024; i += 256) {
    msum += C[i]; dsum += C[1024 + i]; csum += C[2048 + i];
  }
  #pragma unroll
  for (int off = 32; off; off >>= 1) {
    msum += __shfl_xor(msum, off);
    dsum += __shfl_xor(dsum, off);
    csum += __shfl_xor(csum, off);
  }
  int wave = tid >> 6, lane = tid & 63;
  if (lane == 0) { red3[wave] = msum; red3[4 + wave] = dsum; red3[8 + wave] = csum; }
  __syncthreads();
  // KLD terms
  float term = 0.f;
  if (tid < 100) {
    float mc = h[tid], fc = h[100 + tid];
    if (mc > 0.f && fc > 0.f) {
      float p = mc / cnts[0];
      float q = fc / cnts[1];
      term = p * logf(p / q);
    }
  }
  part[tid] = term;
  __syncthreads();
  for (int s = 128; s; s >>= 1) {
    if (tid < s) part[tid] += part[tid + s];
    __syncthreads();
  }
  if (tid == 0) {
    const float invB = 1.0f / (float)B_ROWS;
    float mse = (red3[0] + red3[1] + red3[2] + red3[3]) * invB;
    float dd  = (red3[4] + red3[5] + red3[6] + red3[7]);
    float cc  = (red3[8] + red3[9] + red3[10] + red3[11]);
    float ce  = (cc - dd) * invB;
    float akld = 0.5f * part[0];
    out[0] = 0.5f * (mse + ce) + akld;
    out[1] = mse;
    out[2] = ce;
    out[3] = akld;
  }
}

extern "C" void kernel_launch(void* const* d_in, const int* in_sizes, int n_in,
                              void* d_out, int out_size, void* d_ws, size_t ws_size,
                              hipStream_t stream) {
  const float* enc = (const float*)d_in[0];   // data_encoded (B,12)
  const float* dec = (const float*)d_in[1];   // data_decoded (B,99)
  const float* tru = (const float*)d_in[2];   // data_true    (B,99)
  unsigned int* ws = (unsigned int*)d_ws;
  float* out = (float*)d_out;

  hipLaunchKernelGGL(k_minmax, dim3(128),  dim3(256), 0, stream, enc, ws);
  hipLaunchKernelGGL(k_hist,   dim3(128),  dim3(256), 0, stream, enc, ws);
  hipLaunchKernelGGL(k_main,   dim3(1024), dim3(256), 0, stream, dec, tru, ws);
  hipLaunchKernelGGL(k_final,  dim3(1),    dim3(256), 0, stream, ws, out);
}